// Round 6
// baseline (393.332 us; speedup 1.0000x reference)
//
#include <hip/hip_runtime.h>
#include <hip/hip_bf16.h>

// GCLSTM: B=512, T=32, H=300, K=10. f32 in/out.
// R23 = R22 + T14 async-split on main_split P1/P5: batch-issue all ~9
// uint2 global loads into regs (independent addrs, full MLP), then store
// to LDS; P5 likewise ds_read-batch then global stores. Same p-mapping,
// same order, same barriers as R22 (R21's remap regression not possible).
// VGPR ~56 (<=64 keeps 8 waves/SIMD). XCD swizzle, cells transpose,
// TBF=16 final, merged kprep, ws layouts all byte-frozen from R22.

#define TB 3
#define NBT 171           // ceil(512/3) blocks in b
#define NR 32             // cct rows (MFMA N)
#define NTHR 512          // 8 waves
#define NW 8
#define KP 616
#define TBF 16            // kern_final b-tile (full MFMA M)

// ws layout (u32 slots)
#define OFF_SM    0         // softmax [32][10][512] f32          163840
#define OFF_WBF2  163840    // wp A-frags [mt19][ks19][lane64][4]  92416
#define OFF_F1S   256256    // F1 B-frags [nt13][ks19][lane64][4]  63232
#define OFF_WCELL 319488    // cells B-frags [k10][ht19][g3][l32][4] 72960
#define OFF_BTP   392448    // g*300+h f32                           900
#define OFF_WTP   393348    // (e*3+g)*300+h f32                    3600
#define OFF_F1F   396948    // fuse1 B-frags [nt7][ks10][lane64][4] 17920
#define OFF_WA    414868    // softmax(DisM) f32                      10
#define OFF_SWA   414878    // sum(wA) f32                             1
#define BASE_U32  414880
#define CON1_BYTE ((size_t)BASE_U32 * 4)                  // 1,659,520
#define CONG_BYTE (CON1_BYTE + (size_t)98304000)          // 99,963,520
#define WS_NEED_BYTES (CONG_BYTE + (size_t)98304000)      // 198,267,520 (< proven 198,336,000)

typedef __attribute__((ext_vector_type(8))) short s16x8;
typedef __attribute__((ext_vector_type(4))) float f32x4;
typedef unsigned short u16;

__device__ __forceinline__ float rcpf(float x){ return __builtin_amdgcn_rcpf(x); }
__device__ __forceinline__ float sigf(float x){ return rcpf(1.0f+__expf(-x)); }
__device__ __forceinline__ float tanhf_(float x){ return 1.0f - 2.0f*rcpf(__expf(2.0f*x)+1.0f); }
__device__ __forceinline__ float bfu(u16 u){ return __uint_as_float(((unsigned)u)<<16); }
__device__ __forceinline__ u16 f2us(float f){ return (u16)(__float_as_uint(f)>>16); }
__device__ __forceinline__ u16 f2usr(float f){   // RNE bf16
  __hip_bfloat16 h = __float2bfloat16(f);
  return *(u16*)&h;
}

// ===== cells-MFMA: shuffle-transposed epilogue, uint2 stores (R21) =====
__global__ __launch_bounds__(256,4) void kern_cells(
    const float* __restrict__ li, const float* wsf, u16* __restrict__ cong)
{
  __shared__ __align__(16) float xs[64][12];
  const int tid=threadIdx.x, k=blockIdx.x;
  const int tbase = blockIdx.y*64;
  const int t = tbase>>9, bg0 = tbase&511;
  for (int p=tid; p<64*11; p+=256){
    int r=p/11, i=p%11;
    xs[r][i] = li[(((size_t)(bg0+r)*32+t)*28+i)*10+k];
  }
  if (tid<64) xs[tid][11] = 1.0f;
  __syncthreads();
  const int w = tid>>6, lane = tid&63, lo=lane&15, qd=lane>>4;
  const int c4 = lane&3;            // within 4-lane transpose group
  short av[8];
  #pragma unroll
  for (int j=0;j<8;j++){
    int kk = qd*8+j;
    float v = (kk<12)? xs[w*16+lo][kk] : 0.f;
    av[j] = (short)f2usr(v);
  }
  s16x8 Ax = (s16x8){av[0],av[1],av[2],av[3],av[4],av[5],av[6],av[7]};
  const unsigned* wc = (const unsigned*)wsf + OFF_WCELL;
  const s16x8 Z = (s16x8){0,0,0,0,0,0,0,0};
  // my output row after transpose: tb = tbase + w*16 + qd*4 + c4
  const size_t rowbase = ((size_t)(tbase + w*16 + qd*4 + c4)*10 + k)*300;
  for (int ht=0; ht<19; ht++){
    s16x8 Bi=Z, Bg=Z, Bo=Z;
    if (qd<2){
      const unsigned* bb = wc + (((k*19+ht)*3)*32 + qd*16+lo)*4;
      Bi = *(const s16x8*)(bb);
      Bg = *(const s16x8*)(bb + 32*4);
      Bo = *(const s16x8*)(bb + 64*4);
    }
    f32x4 gi={0.f,0.f,0.f,0.f}, gg={0.f,0.f,0.f,0.f}, go={0.f,0.f,0.f,0.f};
    gi = __builtin_amdgcn_mfma_f32_16x16x32_bf16(Ax, Bi, gi, 0,0,0);
    gg = __builtin_amdgcn_mfma_f32_16x16x32_bf16(Ax, Bg, gg, 0,0,0);
    go = __builtin_amdgcn_mfma_f32_16x16x32_bf16(Ax, Bo, go, 0,0,0);
    float v0 = sigf(go[0]) * tanhf_( sigf(gi[0]) * tanhf_(gg[0]) );
    float v1 = sigf(go[1]) * tanhf_( sigf(gi[1]) * tanhf_(gg[1]) );
    float v2 = sigf(go[2]) * tanhf_( sigf(gi[2]) * tanhf_(gg[2]) );
    float v3 = sigf(go[3]) * tanhf_( sigf(gi[3]) * tanhf_(gg[3]) );
    // 4x4 transpose among lanes differing in c4
    {
      bool hiC = (lane & 2) != 0;
      float s0 = hiC ? v0 : v2;
      float s1 = hiC ? v1 : v3;
      float r0 = __shfl_xor(s0, 2, 64);
      float r1 = __shfl_xor(s1, 2, 64);
      if (hiC){ v0 = r0; v1 = r1; } else { v2 = r0; v3 = r1; }
    }
    {
      bool odd = (lane & 1) != 0;
      float s0 = odd ? v0 : v1;
      float s1 = odd ? v2 : v3;
      float r0 = __shfl_xor(s0, 1, 64);
      float r1 = __shfl_xor(s1, 1, 64);
      if (odd){ v0 = r0; v2 = r1; } else { v1 = r0; v3 = r1; }
    }
    int g = (lane>>2)&3;
    if (!(ht==18 && g==3)){
      uint2 pk;
      pk.x = ((unsigned)f2usr(v1)<<16) | f2usr(v0);
      pk.y = ((unsigned)f2usr(v3)<<16) | f2usr(v2);
      *(uint2*)&cong[rowbase + ht*16 + 4*g] = pk;
    }
  }
}

// ============ kern_main_split (R22 + T14 batch-issue P1/P5) ============
__global__ __launch_bounds__(NTHR,8) void kern_main_split(
    const float* __restrict__ li, const float* __restrict__ exs,
    const float* __restrict__ AngleM, const float* __restrict__ bp,
    const float* __restrict__ F2, const float* __restrict__ b2,
    const float* wsf, unsigned* __restrict__ con1u, float* smg,
    const u16* __restrict__ cong)
{
  __shared__ __align__(16) u16 cct[NR][KP];   // 39,424 B
  __shared__ float xse[TB][2][10];
  __shared__ float exss[TB][4];
  __shared__ float wdP[NW][NR];               // [8][32] = 1,024 B
  __shared__ float wdL[NR];
  const int tid = threadIdx.x;
  // XCD-chunked swizzle: virt = bt*32 + t (5472 = 8*684 exact, bijective)
  const int L = blockIdx.x + NBT*blockIdx.y;      // 0..5471
  const int virt = (L&7)*684 + (L>>3);
  const int bt = virt>>5, t = virt&31, b0 = bt*TB;
  const int w = tid>>6, lane = tid&63, lo = lane&15, qd = lane>>4;

  for (int p=tid;p<TB*20;p+=NTHR){
    int b=p/20, r=p%20, rr=r/10, k=r%10;
    int bg = b0+b; if (bg>511) bg=511;
    xse[b][rr][k] = li[((bg*32+t)*28 + (rr?10:8))*10 + k];
  }
  for (int p=tid;p<TB*4;p+=NTHR){
    int b=p/4, e=p%4;
    int bg = b0+b; if (bg>511) bg=511;
    exss[b][e] = exs[(bg*32+t)*4+e];
  }
  for (int p=tid; p<30*4; p+=NTHR){
    int n=p/4, c=p%4;
    ((unsigned*)&cct[n][600])[c] = 0u;
  }
  __syncthreads();

  // ---- P1 (T14 batched): all loads issued first, then LDS stores ----
  {
    const int nh = (t==0)?1:2;
    const int total = nh*TB*750;
    uint2 vb[9];
    #pragma unroll
    for (int i=0;i<9;i++){
      int p = tid + i*NTHR;
      if (p < total){
        int half=p/(TB*750), r=p%(TB*750), n=r/75, op=r%75;
        int tp = half? t-1 : t;
        int bg = b0 + n/10; if (bg>511) bg=511;
        vb[i] = *(const uint2*)((const unsigned*)cong +
                  ((size_t)(tp*512+bg)*10 + n%10)*150 + 2*op);
      }
    }
    #pragma unroll
    for (int i=0;i<9;i++){
      int p = tid + i*NTHR;
      if (p < total){
        int half=p/(TB*750), r=p%(TB*750), n=r/75, op=r%75;
        *(uint2*)((unsigned*)&cct[n][300*half] + 2*op) = vb[i];
      }
    }
  }
  __syncthreads();

  // ---- P2: wp-MFMA (mt = i*8 + w, i<3) ----
  f32x4 acc[3][2];
  #pragma unroll
  for (int i=0;i<3;i++)
    #pragma unroll
    for (int nt=0;nt<2;nt++) acc[i][nt] = (f32x4){0.f,0.f,0.f,0.f};
  if (t>0){
    const u16* wbfA = (const u16*)((const unsigned*)wsf + OFF_WBF2);
    for (int ks=0; ks<19; ks++){
      const int kb = ks*32 + qd*8;
      s16x8 Bv[2];
      #pragma unroll
      for (int nt=0;nt<2;nt++)
        Bv[nt] = *(const s16x8*)&cct[nt*16+lo][kb];
      #pragma unroll
      for (int i=0;i<3;i++){
        int mt = i*8+w;
        if (mt<19){
          s16x8 Av = *(const s16x8*)(wbfA + ((size_t)(mt*19+ks)*64 + lane)*8);
          #pragma unroll
          for (int nt=0;nt<2;nt++)
            acc[i][nt] = __builtin_amdgcn_mfma_f32_16x16x32_bf16(Av, Bv[nt], acc[i][nt], 0,0,0);
        }
      }
    }
  }
  __syncthreads();

  if (t>0){
    #pragma unroll
    for (int i=0;i<3;i++){
      int mt = i*8+w;
      if (mt<19 && (mt<18 || qd<3)){
        int ob = mt*16 + qd*4;
        float p0=bp[ob], p1=bp[ob+1], p2=bp[ob+2], p3=bp[ob+3];
        #pragma unroll
        for (int nt=0;nt<2;nt++){
          int n = nt*16+lo;
          float v0=acc[i][nt][0]+p0, v1=acc[i][nt][1]+p1,
                v2=acc[i][nt][2]+p2, v3=acc[i][nt][3]+p3;
          unsigned w0 = ((unsigned)f2us(v1>0.f?v1:0.f)<<16) | f2us(v0>0.f?v0:0.f);
          unsigned w1 = ((unsigned)f2us(v3>0.f?v3:0.f)<<16) | f2us(v2>0.f?v2:0.f);
          *(unsigned*)&cct[n][ob]   = w0;
          *(unsigned*)&cct[n][ob+2] = w1;
        }
      }
    }
  }
  // ---- P3: htarget, float4-vectorized (bit-identical accumulation order) ----
  for (int p=tid; p<TB*75; p+=NTHR){
    int b=p/75, q=p%75, o=4*q;
    f32x4 ai={0.f,0.f,0.f,0.f}, ag={0.f,0.f,0.f,0.f}, ao={0.f,0.f,0.f,0.f};
    #pragma unroll
    for (int e=0;e<4;e++){
      float xv = exss[b][e];
      f32x4 wi = *(const f32x4*)&wsf[OFF_WTP+(e*3+0)*300+o];
      f32x4 wg = *(const f32x4*)&wsf[OFF_WTP+(e*3+1)*300+o];
      f32x4 wo = *(const f32x4*)&wsf[OFF_WTP+(e*3+2)*300+o];
      #pragma unroll
      for (int c=0;c<4;c++){
        ai[c] += wi[c]*xv; ag[c] += wg[c]*xv; ao[c] += wo[c]*xv;
      }
    }
    f32x4 bi = *(const f32x4*)&wsf[OFF_BTP+o];
    f32x4 bg = *(const f32x4*)&wsf[OFF_BTP+300+o];
    f32x4 bo = *(const f32x4*)&wsf[OFF_BTP+600+o];
    u16 u[4];
    #pragma unroll
    for (int c=0;c<4;c++){
      float vi = ai[c]+bi[c], vg = ag[c]+bg[c], vo = ao[c]+bo[c];
      u[c] = f2usr( sigf(vo)*tanhf_(sigf(vi)*tanhf_(vg)) );
    }
    uint2 pk;
    pk.x = ((unsigned)u[1]<<16) | u[0];
    pk.y = ((unsigned)u[3]<<16) | u[2];
    #pragma unroll
    for (int k=0;k<10;k++)
      *(uint2*)&cct[b*10+k][300+o] = pk;
  }
  for (int p=tid; p<30*4; p+=NTHR){
    int n=p/4, c=p%4;
    ((unsigned*)&cct[n][600])[c] = (c==0)? 0x00003f80u : 0u;
  }
  __syncthreads();

  // ---- P5 (T14 batched): ds_reads first, then global stores ----
  {
    uint2 vb[5];
    #pragma unroll
    for (int i=0;i<5;i++){
      int p = tid + i*NTHR;
      if (p < TB*750){
        int n=p/75, op=p%75;
        vb[i] = *(const uint2*)((unsigned*)&cct[n][0] + 2*op);
      }
    }
    #pragma unroll
    for (int i=0;i<5;i++){
      int p = tid + i*NTHR;
      if (p < TB*750){
        int n=p/75, op=p%75;
        int bg = b0 + n/10;
        if (bg < 512)
          *(uint2*)(con1u + ((size_t)(t*512+bg)*10 + n%10)*150 + 2*op) = vb[i];
      }
    }
  }

  // ---- P4: F1-MFMA (nt = w + j*8) ----
  f32x4 acc2[2][2];
  #pragma unroll
  for (int mt=0;mt<2;mt++)
    #pragma unroll
    for (int j=0;j<2;j++) acc2[mt][j] = (f32x4){0.f,0.f,0.f,0.f};
  {
    const u16* f1s = (const u16*)((const unsigned*)wsf + OFF_F1S);
    for (int ks=0; ks<19; ks++){
      const int kb = ks*32 + qd*8;
      s16x8 Am[2];
      #pragma unroll
      for (int mt=0;mt<2;mt++)
        Am[mt] = *(const s16x8*)&cct[mt*16+lo][kb];
      #pragma unroll
      for (int j=0;j<2;j++){
        int nt = w + j*8;
        if (nt<13){
          s16x8 Bf = *(const s16x8*)(f1s + ((size_t)(nt*19+ks)*64 + lane)*8);
          #pragma unroll
          for (int mt=0;mt<2;mt++)
            acc2[mt][j] = __builtin_amdgcn_mfma_f32_16x16x32_bf16(Am[mt], Bf, acc2[mt][j], 0,0,0);
        }
      }
    }
  }
  {
    float f2c[2];
    #pragma unroll
    for (int j=0;j<2;j++){
      int nt = w + j*8;
      int jj = nt*16+lo;
      f2c[j] = (nt<13 && jj<200)? F2[jj] : 0.f;
    }
    #pragma unroll
    for (int mt=0;mt<2;mt++)
      #pragma unroll
      for (int r=0;r<4;r++){
        float s = 0.f;
        #pragma unroll
        for (int j=0;j<2;j++){
          float v = acc2[mt][j][r];
          s += (v>0.f? v:0.f) * f2c[j];
        }
        s += __shfl_xor(s,1,64); s += __shfl_xor(s,2,64);
        s += __shfl_xor(s,4,64); s += __shfl_xor(s,8,64);
        if (lo==0) wdP[w][mt*16+qd*4+r] = s;
      }
  }
  __syncthreads();
  if (tid<TB*10){
    int n=tid, b=n/10, k=n%10;
    float v = 0.f;
    #pragma unroll
    for (int ww=0;ww<NW;ww++) v += wdP[ww][n];
    float ang = fabsf(xse[b][1][k]-AngleM[k]) * (1.0f/360.0f);
    v += xse[b][0][k]*F2[200] + ang*F2[201] + b2[0];
    wdL[n] = v>0.f? v : 0.f;
  }
  __syncthreads();
  if (tid<TB && b0+tid < 512){
    int b=tid;
    float m = wdL[b*10];
    #pragma unroll
    for (int k=1;k<10;k++) m = fmaxf(m, wdL[b*10+k]);
    float e[10]; float s=0.f;
    #pragma unroll
    for (int k=0;k<10;k++){ e[k]=__expf(wdL[b*10+k]-m); s+=e[k]; }
    float inv = rcpf(s);
    #pragma unroll
    for (int k=0;k<10;k++) smg[t*5120 + k*512 + b0+b] = e[k]*inv;
  }
}

// ====== final: TBF=16, full-M fuse1 MFMA, cats direct from global ======
__global__ __launch_bounds__(NTHR,8) void kern_final(
    const float* __restrict__ li, const float* __restrict__ labels,
    const float* __restrict__ ff, const float* __restrict__ bff,
    const float* __restrict__ biasf, const float* __restrict__ Wout,
    const float* __restrict__ biasout, const float* __restrict__ a,
    const float* wsf, const unsigned* __restrict__ con1u,
    float* __restrict__ outp)
{
  __shared__ __align__(16) float cats[TBF][324];   // stride 324: rows 4 banks apart
  __shared__ __align__(16) float xs17[TBF][17][10];
  __shared__ float wa3s[TBF][10];
  __shared__ float dss[TBF][17];
  __shared__ float wAs[10];
  __shared__ float part[7][TBF];
  const int tid=threadIdx.x, t=blockIdx.y, bt=blockIdx.x, b0=bt*TBF;
  const int w = tid>>6, lane = tid&63, lo = lane&15, qd = lane>>4;
  if (tid>=NTHR-TBF){   // fused labels_r copy
    int b = tid-(NTHR-TBF);
    outp[16384 + t*512 + b0+b] = labels[(b0+b)*32+t];
  }
  for (int p=tid;p<TBF*85;p+=NTHR){   // float2 xs17 loads (k-pairs)
    int b=p/85, r=p%85, f=r/5, pr=r%5;
    *(float2*)&xs17[b][f][2*pr] =
        *(const float2*)&li[(((b0+b)*32+t)*28 + 11+f)*10 + 2*pr];
  }
  if (tid<10) wAs[tid] = wsf[OFF_WA+tid];
  for (int p=tid;p<TBF*10;p+=NTHR){
    int b=p/10, k=p%10;
    int g = (b0+b)*10+k;   // flat-reshape scramble
    wa3s[b][k] = wsf[OFF_SM + t*5120 + (g>>9)*512 + (g&511)];
  }
  __syncthreads();
  for (int p=tid;p<TBF*17;p+=NTHR){
    int b=p/17, f=p%17; float s=0.f;
    #pragma unroll
    for (int k=0;k<10;k++) s += xs17[b][f][k]*wAs[k];
    dss[b][f]=s;
  }
  // cats straight from global con1u (coalesced uint2; same sum order)
  for (int p=tid;p<TBF*75;p+=NTHR){
    int b=p/75, q=p%75, o=4*q;
    const unsigned* base = con1u + ((size_t)(t*512 + b0+b)*10)*150 + 2*q;
    f32x4 s = {0.f,0.f,0.f,0.f};
    #pragma unroll
    for (int k=0;k<10;k++){
      uint2 cv = *(const uint2*)(base + (size_t)k*150);
      float wk = wa3s[b][k];
      s[0] += bfu((u16)(cv.x & 0xffffu))*wk;
      s[1] += bfu((u16)(cv.x >> 16))*wk;
      s[2] += bfu((u16)(cv.y & 0xffffu))*wk;
      s[3] += bfu((u16)(cv.y >> 16))*wk;
    }
    *(f32x4*)&cats[b][o] = s;
  }
  for (int p=tid;p<TBF*6;p+=NTHR){   // zero cols 300-323
    int b=p/6, c=p%6;
    *(f32x4*)&cats[b][300+4*c] = (f32x4){0.f,0.f,0.f,0.f};
  }
  __syncthreads();
  // ---- fuse1 MFMA: D[b 16][o 112] = cats[16x320] @ fuse1[320x112]; wave=Ntile ----
  if (w < 7){
    f32x4 D = (f32x4){0.f,0.f,0.f,0.f};
    const u16* f1f = (const u16*)((const unsigned*)wsf + OFF_F1F);
    for (int ks=0; ks<10; ks++){
      const int kb = ks*32 + qd*8;
      f32x4 c0 = *(const f32x4*)&cats[lo][kb];
      f32x4 c1 = *(const f32x4*)&cats[lo][kb+4];
      short av[8];
      #pragma unroll
      for (int j=0;j<4;j++){
        av[j]   = (short)f2usr(c0[j]);
        av[4+j] = (short)f2usr(c1[j]);
      }
      s16x8 Ax = (s16x8){av[0],av[1],av[2],av[3],av[4],av[5],av[6],av[7]};
      s16x8 Bf = *(const s16x8*)(f1f + ((size_t)(w*10+ks)*64 + lane)*8);
      D = __builtin_amdgcn_mfma_f32_16x16x32_bf16(Ax, Bf, D, 0,0,0);
    }
    {   // epilogue, all lanes: row = qd*4+r = batch, col = w*16+lo = o
      int o = w*16+lo;
      bool ov = o<100;
      float aa = a[0], swa = wsf[OFF_SWA];
      float bfo = ov? biasf[o] : 0.f;
      float bffo = ov? bff[o]*swa : 0.f;
      float wo = ov? Wout[o] : 0.f;
      #pragma unroll
      for (int r=0;r<4;r++){
        int b = qd*4+r;
        float fu = D[r] + bfo;
        float fd = bffo;
        if (ov){
          #pragma unroll
          for (int f=0;f<17;f++) fd += ff[o*17+f]*dss[b][f];
        }
        float v = (aa*fu + (1.f-aa)*fd) * wo;
        v += __shfl_xor(v,1,64); v += __shfl_xor(v,2,64);
        v += __shfl_xor(v,4,64); v += __shfl_xor(v,8,64);
        if (lo==0) part[w][b] = v;
      }
    }
  }
  __syncthreads();
  if (tid<TBF){
    int b=tid;
    float v = biasout[0];
    #pragma unroll
    for (int ww=0;ww<7;ww++) v += part[ww][b];
    outp[t*512 + b0+b] = v;
  }
}

// ================= weight prep (kprep2 folded into tail thread) =================
__global__ void kprep(const float* __restrict__ Wih, const float* __restrict__ b_ih,
                      const float* __restrict__ b_hh, const float* __restrict__ Wt,
                      const float* __restrict__ bt_ih, const float* __restrict__ bt_hh,
                      const float* __restrict__ wp, const float* __restrict__ F1,
                      const float* __restrict__ b1, const float* __restrict__ fuse1,
                      const float* __restrict__ DisM, float* __restrict__ wsf)
{
  int n = blockIdx.x*256 + threadIdx.x;
  if (n < 92416){   // wp A-frags
    int jp=n&3, lane=(n>>2)&63, rest=n>>8;
    int ks=rest%19, mt=rest/19;
    int m = mt*16 + (lane&15);
    int k = ks*32 + (lane>>4)*8 + 2*jp;
    float v0 = (m<300 && k  <600)? wp[m*600+k  ] : 0.f;
    float v1 = (m<300 && k+1<600)? wp[m*600+k+1] : 0.f;
    ((unsigned*)wsf)[OFF_WBF2+n] = ((unsigned)f2usr(v1)<<16) | f2usr(v0);
    return;
  }
  n -= 92416;
  if (n < 63232){   // F1 B-frags; row 600 = b1
    int jp=n&3, lane=(n>>2)&63, rest=n>>8;
    int ks=rest%19, nt=rest/19;
    int col = nt*16 + (lane&15);
    int k = ks*32 + (lane>>4)*8 + 2*jp;
    float v0=0.f, v1=0.f;
    if (col<200){
      v0 = (k  <600)? F1[k*200+col]     : (k  ==600? b1[col] : 0.f);
      v1 = (k+1<600)? F1[(k+1)*200+col] : (k+1==600? b1[col] : 0.f);
    }
    ((unsigned*)wsf)[OFF_F1S+n] = ((unsigned)f2usr(v1)<<16) | f2usr(v0);
    return;
  }
  n -= 63232;
  if (n < 72960){   // cells B-frags
    int jp=n&3, l32=(n>>2)&31, rest=n>>7;
    int g=rest%3, rest2=rest/3, ht=rest2%19, k=rest2/19;
    int lo=l32&15, q16=l32>>4;
    int h = ht*16 + lo;
    int kk0 = q16*8 + 2*jp;
    float v0=0.f, v1=0.f;
    if (h < 300){
      int G = h + (g==0?0:(g==1?600:900));
      v0 = (kk0  <11)? Wih[(k*1200+G)*11+kk0]
         : (kk0 ==11? b_ih[k*1200+G]+b_hh[k*1200+G] : 0.f);
      int kk1 = kk0+1;
      v1 = (kk1  <11)? Wih[(k*1200+G)*11+kk1]
         : (kk1 ==11? b_ih[k*1200+G]+b_hh[k*1200+G] : 0.f);
    }
    ((unsigned*)wsf)[OFF_WCELL+n] = ((unsigned)f2usr(v1)<<16) | f2usr(v0);
    return;
  }
  n -= 72960;
  if (n < 900){
    int h=n%300, g=n/300;
    int G = h + (g==0?0:(g==1?600:900));
    wsf[OFF_BTP+n] = bt_ih[G]+bt_hh[G]; return;
  }
  n -= 900;
  if (n < 3600){
    int h=n%300; int q=n/300; int g=q%3, e=q/3;
    int G = h + (g==0?0:(g==1?600:900));
    wsf[OFF_WTP+n] = Wt[G*4+e]; return;
  }
  n -= 3600;
  if (n < 17920){   // fuse1 B-frags [nt7][ks10][lane][4]: B[kk][o], kk<300, o<100
    int jp=n&3, lane=(n>>2)&63, rest=n>>8;
    int ks=rest%10, nt=rest/10;
    int col = nt*16 + (lane&15);
    int kk0 = ks*32 + (lane>>4)*8 + 2*jp;
    float v0 = (col<100 && kk0  <300)? fuse1[kk0*100+col]     : 0.f;
    float v1 = (col<100 && kk0+1<300)? fuse1[(kk0+1)*100+col] : 0.f;
    ((unsigned*)wsf)[OFF_F1F+n] = ((unsigned)f2usr(v1)<<16) | f2usr(v0);
    return;
  }
  n -= 17920;
  if (n == 0){   // former kprep2: softmax(DisM) + sum (independent ws region)
    float m = DisM[0];
    for (int k=1;k<10;k++) m = fmaxf(m, DisM[k]);
    float e[10]; float s=0.f;
    for (int k=0;k<10;k++){ e[k]=__expf(DisM[k]-m); s+=e[k]; }
    float inv=1.0f/s; float sw=0.f;
    for (int k=0;k<10;k++){ float v=e[k]*inv; wsf[OFF_WA+k]=v; sw+=v; }
    wsf[OFF_SWA]=sw;
  }
}

extern "C" void kernel_launch(void* const* d_in, const int* in_sizes, int n_in,
                              void* d_out, int out_size, void* d_ws, size_t ws_size,
                              hipStream_t stream)
{
  const float* li     = (const float*)d_in[0];
  const float* labels = (const float*)d_in[1];
  const float* exs    = (const float*)d_in[2];
  const float* DisM   = (const float*)d_in[3];
  const float* AngleM = (const float*)d_in[4];
  const float* Wih    = (const float*)d_in[5];
  const float* b_ih   = (const float*)d_in[6];
  const float* b_hh   = (const float*)d_in[7];
  const float* Wt     = (const float*)d_in[8];
  const float* bt_ih  = (const float*)d_in[9];
  const float* bt_hh  = (const float*)d_in[10];
  const float* wp     = (const float*)d_in[11];
  const float* bp     = (const float*)d_in[12];
  const float* F1     = (const float*)d_in[13];
  const float* b1     = (const float*)d_in[14];
  const float* F2     = (const float*)d_in[15];
  const float* b2     = (const float*)d_in[16];
  const float* ff     = (const float*)d_in[17];
  const float* bff    = (const float*)d_in[18];
  const float* fuse1  = (const float*)d_in[19];
  const float* biasf  = (const float*)d_in[20];
  const float* Wout   = (const float*)d_in[21];
  const float* biasout= (const float*)d_in[22];
  const float* a      = (const float*)d_in[23];
  float* wsf = (float*)d_ws;
  float* outp = (float*)d_out;
  unsigned* con1u = (unsigned*)((char*)d_ws + CON1_BYTE);
  u16* cong = (u16*)((char*)d_ws + CONG_BYTE);

  if (ws_size < WS_NEED_BYTES) return;  // proven available (R12 split ran)

  kprep<<<dim3(981), dim3(256), 0, stream>>>(Wih,b_ih,b_hh,Wt,bt_ih,bt_hh,wp,F1,b1,fuse1,DisM,wsf);
  kern_cells<<<dim3(10,256), dim3(256), 0, stream>>>(li, wsf, cong);
  kern_main_split<<<dim3(NBT,32), NTHR, 0, stream>>>(li, exs, AngleM, bp, F2, b2,
                                                     wsf, con1u, wsf + OFF_SM, cong);
  kern_final<<<dim3(32,32), NTHR, 0, stream>>>(li, labels, ff, bff, biasf,
                                               Wout, biasout, a, wsf, con1u, outp);
}

// Round 7
// 376.836 us; speedup vs baseline: 1.0438x; 1.0438x over previous
//
#include <hip/hip_runtime.h>
#include <hip/hip_bf16.h>

// GCLSTM: B=512, T=32, H=300, K=10. f32 in/out.
// R24 = R22 exactly (best known: 382us; R23's P1/P5 batch-issue REVERTED,
// second reordering regression) + XCD-chunk swizzle on kern_cells: the 10
// k-blocks per row-chunk share every li cache line (k is the contiguous
// 40B axis); remap L (2560=8*320, bijective) so each XCD owns complete
// chunks with all 10 k -> li re-fetch resolves in its own L2 (same
// mechanism as R22's main_split swizzle, FETCH -49% there). Data path,
// LDS, stores byte-identical. main_split/final/kprep frozen from R22.

#define TB 3
#define NBT 171           // ceil(512/3) blocks in b
#define NR 32             // cct rows (MFMA N)
#define NTHR 512          // 8 waves
#define NW 8
#define KP 616
#define TBF 16            // kern_final b-tile (full MFMA M)

// ws layout (u32 slots)
#define OFF_SM    0         // softmax [32][10][512] f32          163840
#define OFF_WBF2  163840    // wp A-frags [mt19][ks19][lane64][4]  92416
#define OFF_F1S   256256    // F1 B-frags [nt13][ks19][lane64][4]  63232
#define OFF_WCELL 319488    // cells B-frags [k10][ht19][g3][l32][4] 72960
#define OFF_BTP   392448    // g*300+h f32                           900
#define OFF_WTP   393348    // (e*3+g)*300+h f32                    3600
#define OFF_F1F   396948    // fuse1 B-frags [nt7][ks10][lane64][4] 17920
#define OFF_WA    414868    // softmax(DisM) f32                      10
#define OFF_SWA   414878    // sum(wA) f32                             1
#define BASE_U32  414880
#define CON1_BYTE ((size_t)BASE_U32 * 4)                  // 1,659,520
#define CONG_BYTE (CON1_BYTE + (size_t)98304000)          // 99,963,520
#define WS_NEED_BYTES (CONG_BYTE + (size_t)98304000)      // 198,267,520 (< proven 198,336,000)

typedef __attribute__((ext_vector_type(8))) short s16x8;
typedef __attribute__((ext_vector_type(4))) float f32x4;
typedef unsigned short u16;

__device__ __forceinline__ float rcpf(float x){ return __builtin_amdgcn_rcpf(x); }
__device__ __forceinline__ float sigf(float x){ return rcpf(1.0f+__expf(-x)); }
__device__ __forceinline__ float tanhf_(float x){ return 1.0f - 2.0f*rcpf(__expf(2.0f*x)+1.0f); }
__device__ __forceinline__ float bfu(u16 u){ return __uint_as_float(((unsigned)u)<<16); }
__device__ __forceinline__ u16 f2us(float f){ return (u16)(__float_as_uint(f)>>16); }
__device__ __forceinline__ u16 f2usr(float f){   // RNE bf16
  __hip_bfloat16 h = __float2bfloat16(f);
  return *(u16*)&h;
}

// ===== cells-MFMA: shuffle-transposed epilogue + XCD-chunk swizzle =====
__global__ __launch_bounds__(256,4) void kern_cells(
    const float* __restrict__ li, const float* wsf, u16* __restrict__ cong)
{
  __shared__ __align__(16) float xs[64][12];
  const int tid=threadIdx.x;
  // XCD-chunk swizzle: 2560 = 8*320 exact. virt = chunk*10 + k, so XCD x
  // owns chunks [32x,32x+32) with ALL 10 k -> shared li lines hit own L2.
  const int L = blockIdx.x + 10*blockIdx.y;
  const int virt = (L&7)*320 + (L>>3);
  const int k = virt%10;
  const int tbase = (virt/10)*64;
  const int t = tbase>>9, bg0 = tbase&511;
  for (int p=tid; p<64*11; p+=256){
    int r=p/11, i=p%11;
    xs[r][i] = li[(((size_t)(bg0+r)*32+t)*28+i)*10+k];
  }
  if (tid<64) xs[tid][11] = 1.0f;
  __syncthreads();
  const int w = tid>>6, lane = tid&63, lo=lane&15, qd=lane>>4;
  const int c4 = lane&3;            // within 4-lane transpose group
  short av[8];
  #pragma unroll
  for (int j=0;j<8;j++){
    int kk = qd*8+j;
    float v = (kk<12)? xs[w*16+lo][kk] : 0.f;
    av[j] = (short)f2usr(v);
  }
  s16x8 Ax = (s16x8){av[0],av[1],av[2],av[3],av[4],av[5],av[6],av[7]};
  const unsigned* wc = (const unsigned*)wsf + OFF_WCELL;
  const s16x8 Z = (s16x8){0,0,0,0,0,0,0,0};
  // my output row after transpose: tb = tbase + w*16 + qd*4 + c4
  const size_t rowbase = ((size_t)(tbase + w*16 + qd*4 + c4)*10 + k)*300;
  for (int ht=0; ht<19; ht++){
    s16x8 Bi=Z, Bg=Z, Bo=Z;
    if (qd<2){
      const unsigned* bb = wc + (((k*19+ht)*3)*32 + qd*16+lo)*4;
      Bi = *(const s16x8*)(bb);
      Bg = *(const s16x8*)(bb + 32*4);
      Bo = *(const s16x8*)(bb + 64*4);
    }
    f32x4 gi={0.f,0.f,0.f,0.f}, gg={0.f,0.f,0.f,0.f}, go={0.f,0.f,0.f,0.f};
    gi = __builtin_amdgcn_mfma_f32_16x16x32_bf16(Ax, Bi, gi, 0,0,0);
    gg = __builtin_amdgcn_mfma_f32_16x16x32_bf16(Ax, Bg, gg, 0,0,0);
    go = __builtin_amdgcn_mfma_f32_16x16x32_bf16(Ax, Bo, go, 0,0,0);
    float v0 = sigf(go[0]) * tanhf_( sigf(gi[0]) * tanhf_(gg[0]) );
    float v1 = sigf(go[1]) * tanhf_( sigf(gi[1]) * tanhf_(gg[1]) );
    float v2 = sigf(go[2]) * tanhf_( sigf(gi[2]) * tanhf_(gg[2]) );
    float v3 = sigf(go[3]) * tanhf_( sigf(gi[3]) * tanhf_(gg[3]) );
    // 4x4 transpose among lanes differing in c4
    {
      bool hiC = (lane & 2) != 0;
      float s0 = hiC ? v0 : v2;
      float s1 = hiC ? v1 : v3;
      float r0 = __shfl_xor(s0, 2, 64);
      float r1 = __shfl_xor(s1, 2, 64);
      if (hiC){ v0 = r0; v1 = r1; } else { v2 = r0; v3 = r1; }
    }
    {
      bool odd = (lane & 1) != 0;
      float s0 = odd ? v0 : v1;
      float s1 = odd ? v2 : v3;
      float r0 = __shfl_xor(s0, 1, 64);
      float r1 = __shfl_xor(s1, 1, 64);
      if (odd){ v0 = r0; v2 = r1; } else { v1 = r0; v3 = r1; }
    }
    int g = (lane>>2)&3;
    if (!(ht==18 && g==3)){
      uint2 pk;
      pk.x = ((unsigned)f2usr(v1)<<16) | f2usr(v0);
      pk.y = ((unsigned)f2usr(v3)<<16) | f2usr(v2);
      *(uint2*)&cong[rowbase + ht*16 + 4*g] = pk;
    }
  }
}

// ============ kern_main_split (R22: R20 body + XCD-chunked swizzle) ============
__global__ __launch_bounds__(NTHR,8) void kern_main_split(
    const float* __restrict__ li, const float* __restrict__ exs,
    const float* __restrict__ AngleM, const float* __restrict__ bp,
    const float* __restrict__ F2, const float* __restrict__ b2,
    const float* wsf, unsigned* __restrict__ con1u, float* smg,
    const u16* __restrict__ cong)
{
  __shared__ __align__(16) u16 cct[NR][KP];   // 39,424 B
  __shared__ float xse[TB][2][10];
  __shared__ float exss[TB][4];
  __shared__ float wdP[NW][NR];               // [8][32] = 1,024 B
  __shared__ float wdL[NR];
  const int tid = threadIdx.x;
  // XCD-chunked swizzle: virt = bt*32 + t (5472 = 8*684 exact, bijective)
  const int L = blockIdx.x + NBT*blockIdx.y;      // 0..5471
  const int virt = (L&7)*684 + (L>>3);
  const int bt = virt>>5, t = virt&31, b0 = bt*TB;
  const int w = tid>>6, lane = tid&63, lo = lane&15, qd = lane>>4;

  for (int p=tid;p<TB*20;p+=NTHR){
    int b=p/20, r=p%20, rr=r/10, k=r%10;
    int bg = b0+b; if (bg>511) bg=511;
    xse[b][rr][k] = li[((bg*32+t)*28 + (rr?10:8))*10 + k];
  }
  for (int p=tid;p<TB*4;p+=NTHR){
    int b=p/4, e=p%4;
    int bg = b0+b; if (bg>511) bg=511;
    exss[b][e] = exs[(bg*32+t)*4+e];
  }
  for (int p=tid; p<30*4; p+=NTHR){
    int n=p/4, c=p%4;
    ((unsigned*)&cct[n][600])[c] = 0u;
  }
  __syncthreads();

  // ---- P1: uint2 copies; con(t) -> cols 0-299, con(t-1) -> cols 300-599 ----
  const int nh = (t==0)?1:2;
  for (int p=tid; p<nh*TB*750; p+=NTHR){
    int half=p/(TB*750), r=p%(TB*750), n=r/75, op=r%75;
    int tp = half? t-1 : t;
    int bg = b0 + n/10; if (bg>511) bg=511;
    uint2 v = *(const uint2*)((const unsigned*)cong +
                ((size_t)(tp*512+bg)*10 + n%10)*150 + 2*op);
    *(uint2*)((unsigned*)&cct[n][300*half] + 2*op) = v;
  }
  __syncthreads();

  // ---- P2: wp-MFMA (mt = i*8 + w, i<3) ----
  f32x4 acc[3][2];
  #pragma unroll
  for (int i=0;i<3;i++)
    #pragma unroll
    for (int nt=0;nt<2;nt++) acc[i][nt] = (f32x4){0.f,0.f,0.f,0.f};
  if (t>0){
    const u16* wbfA = (const u16*)((const unsigned*)wsf + OFF_WBF2);
    for (int ks=0; ks<19; ks++){
      const int kb = ks*32 + qd*8;
      s16x8 Bv[2];
      #pragma unroll
      for (int nt=0;nt<2;nt++)
        Bv[nt] = *(const s16x8*)&cct[nt*16+lo][kb];
      #pragma unroll
      for (int i=0;i<3;i++){
        int mt = i*8+w;
        if (mt<19){
          s16x8 Av = *(const s16x8*)(wbfA + ((size_t)(mt*19+ks)*64 + lane)*8);
          #pragma unroll
          for (int nt=0;nt<2;nt++)
            acc[i][nt] = __builtin_amdgcn_mfma_f32_16x16x32_bf16(Av, Bv[nt], acc[i][nt], 0,0,0);
        }
      }
    }
  }
  __syncthreads();

  if (t>0){
    #pragma unroll
    for (int i=0;i<3;i++){
      int mt = i*8+w;
      if (mt<19 && (mt<18 || qd<3)){
        int ob = mt*16 + qd*4;
        float p0=bp[ob], p1=bp[ob+1], p2=bp[ob+2], p3=bp[ob+3];
        #pragma unroll
        for (int nt=0;nt<2;nt++){
          int n = nt*16+lo;
          float v0=acc[i][nt][0]+p0, v1=acc[i][nt][1]+p1,
                v2=acc[i][nt][2]+p2, v3=acc[i][nt][3]+p3;
          unsigned w0 = ((unsigned)f2us(v1>0.f?v1:0.f)<<16) | f2us(v0>0.f?v0:0.f);
          unsigned w1 = ((unsigned)f2us(v3>0.f?v3:0.f)<<16) | f2us(v2>0.f?v2:0.f);
          *(unsigned*)&cct[n][ob]   = w0;
          *(unsigned*)&cct[n][ob+2] = w1;
        }
      }
    }
  }
  // ---- P3: htarget, float4-vectorized (bit-identical accumulation order) ----
  for (int p=tid; p<TB*75; p+=NTHR){
    int b=p/75, q=p%75, o=4*q;
    f32x4 ai={0.f,0.f,0.f,0.f}, ag={0.f,0.f,0.f,0.f}, ao={0.f,0.f,0.f,0.f};
    #pragma unroll
    for (int e=0;e<4;e++){
      float xv = exss[b][e];
      f32x4 wi = *(const f32x4*)&wsf[OFF_WTP+(e*3+0)*300+o];
      f32x4 wg = *(const f32x4*)&wsf[OFF_WTP+(e*3+1)*300+o];
      f32x4 wo = *(const f32x4*)&wsf[OFF_WTP+(e*3+2)*300+o];
      #pragma unroll
      for (int c=0;c<4;c++){
        ai[c] += wi[c]*xv; ag[c] += wg[c]*xv; ao[c] += wo[c]*xv;
      }
    }
    f32x4 bi = *(const f32x4*)&wsf[OFF_BTP+o];
    f32x4 bg = *(const f32x4*)&wsf[OFF_BTP+300+o];
    f32x4 bo = *(const f32x4*)&wsf[OFF_BTP+600+o];
    u16 u[4];
    #pragma unroll
    for (int c=0;c<4;c++){
      float vi = ai[c]+bi[c], vg = ag[c]+bg[c], vo = ao[c]+bo[c];
      u[c] = f2usr( sigf(vo)*tanhf_(sigf(vi)*tanhf_(vg)) );
    }
    uint2 pk;
    pk.x = ((unsigned)u[1]<<16) | u[0];
    pk.y = ((unsigned)u[3]<<16) | u[2];
    #pragma unroll
    for (int k=0;k<10;k++)
      *(uint2*)&cct[b*10+k][300+o] = pk;
  }
  for (int p=tid; p<30*4; p+=NTHR){
    int n=p/4, c=p%4;
    ((unsigned*)&cct[n][600])[c] = (c==0)? 0x00003f80u : 0u;
  }
  __syncthreads();

  // ---- P5: uint2 stores of con1 tile ----
  for (int p=tid; p<TB*750; p+=NTHR){
    int n=p/75, op=p%75;
    int bg = b0 + n/10;
    if (bg < 512){
      uint2 v = *(const uint2*)((unsigned*)&cct[n][0] + 2*op);
      *(uint2*)(con1u + ((size_t)(t*512+bg)*10 + n%10)*150 + 2*op) = v;
    }
  }

  // ---- P4: F1-MFMA (nt = w + j*8) ----
  f32x4 acc2[2][2];
  #pragma unroll
  for (int mt=0;mt<2;mt++)
    #pragma unroll
    for (int j=0;j<2;j++) acc2[mt][j] = (f32x4){0.f,0.f,0.f,0.f};
  {
    const u16* f1s = (const u16*)((const unsigned*)wsf + OFF_F1S);
    for (int ks=0; ks<19; ks++){
      const int kb = ks*32 + qd*8;
      s16x8 Am[2];
      #pragma unroll
      for (int mt=0;mt<2;mt++)
        Am[mt] = *(const s16x8*)&cct[mt*16+lo][kb];
      #pragma unroll
      for (int j=0;j<2;j++){
        int nt = w + j*8;
        if (nt<13){
          s16x8 Bf = *(const s16x8*)(f1s + ((size_t)(nt*19+ks)*64 + lane)*8);
          #pragma unroll
          for (int mt=0;mt<2;mt++)
            acc2[mt][j] = __builtin_amdgcn_mfma_f32_16x16x32_bf16(Am[mt], Bf, acc2[mt][j], 0,0,0);
        }
      }
    }
  }
  {
    float f2c[2];
    #pragma unroll
    for (int j=0;j<2;j++){
      int nt = w + j*8;
      int jj = nt*16+lo;
      f2c[j] = (nt<13 && jj<200)? F2[jj] : 0.f;
    }
    #pragma unroll
    for (int mt=0;mt<2;mt++)
      #pragma unroll
      for (int r=0;r<4;r++){
        float s = 0.f;
        #pragma unroll
        for (int j=0;j<2;j++){
          float v = acc2[mt][j][r];
          s += (v>0.f? v:0.f) * f2c[j];
        }
        s += __shfl_xor(s,1,64); s += __shfl_xor(s,2,64);
        s += __shfl_xor(s,4,64); s += __shfl_xor(s,8,64);
        if (lo==0) wdP[w][mt*16+qd*4+r] = s;
      }
  }
  __syncthreads();
  if (tid<TB*10){
    int n=tid, b=n/10, k=n%10;
    float v = 0.f;
    #pragma unroll
    for (int ww=0;ww<NW;ww++) v += wdP[ww][n];
    float ang = fabsf(xse[b][1][k]-AngleM[k]) * (1.0f/360.0f);
    v += xse[b][0][k]*F2[200] + ang*F2[201] + b2[0];
    wdL[n] = v>0.f? v : 0.f;
  }
  __syncthreads();
  if (tid<TB && b0+tid < 512){
    int b=tid;
    float m = wdL[b*10];
    #pragma unroll
    for (int k=1;k<10;k++) m = fmaxf(m, wdL[b*10+k]);
    float e[10]; float s=0.f;
    #pragma unroll
    for (int k=0;k<10;k++){ e[k]=__expf(wdL[b*10+k]-m); s+=e[k]; }
    float inv = rcpf(s);
    #pragma unroll
    for (int k=0;k<10;k++) smg[t*5120 + k*512 + b0+b] = e[k]*inv;
  }
}

// ====== final: TBF=16, full-M fuse1 MFMA, cats direct from global ======
__global__ __launch_bounds__(NTHR,8) void kern_final(
    const float* __restrict__ li, const float* __restrict__ labels,
    const float* __restrict__ ff, const float* __restrict__ bff,
    const float* __restrict__ biasf, const float* __restrict__ Wout,
    const float* __restrict__ biasout, const float* __restrict__ a,
    const float* wsf, const unsigned* __restrict__ con1u,
    float* __restrict__ outp)
{
  __shared__ __align__(16) float cats[TBF][324];   // stride 324: rows 4 banks apart
  __shared__ __align__(16) float xs17[TBF][17][10];
  __shared__ float wa3s[TBF][10];
  __shared__ float dss[TBF][17];
  __shared__ float wAs[10];
  __shared__ float part[7][TBF];
  const int tid=threadIdx.x, t=blockIdx.y, bt=blockIdx.x, b0=bt*TBF;
  const int w = tid>>6, lane = tid&63, lo = lane&15, qd = lane>>4;
  if (tid>=NTHR-TBF){   // fused labels_r copy
    int b = tid-(NTHR-TBF);
    outp[16384 + t*512 + b0+b] = labels[(b0+b)*32+t];
  }
  for (int p=tid;p<TBF*85;p+=NTHR){   // float2 xs17 loads (k-pairs)
    int b=p/85, r=p%85, f=r/5, pr=r%5;
    *(float2*)&xs17[b][f][2*pr] =
        *(const float2*)&li[(((b0+b)*32+t)*28 + 11+f)*10 + 2*pr];
  }
  if (tid<10) wAs[tid] = wsf[OFF_WA+tid];
  for (int p=tid;p<TBF*10;p+=NTHR){
    int b=p/10, k=p%10;
    int g = (b0+b)*10+k;   // flat-reshape scramble
    wa3s[b][k] = wsf[OFF_SM + t*5120 + (g>>9)*512 + (g&511)];
  }
  __syncthreads();
  for (int p=tid;p<TBF*17;p+=NTHR){
    int b=p/17, f=p%17; float s=0.f;
    #pragma unroll
    for (int k=0;k<10;k++) s += xs17[b][f][k]*wAs[k];
    dss[b][f]=s;
  }
  // cats straight from global con1u (coalesced uint2; same sum order)
  for (int p=tid;p<TBF*75;p+=NTHR){
    int b=p/75, q=p%75, o=4*q;
    const unsigned* base = con1u + ((size_t)(t*512 + b0+b)*10)*150 + 2*q;
    f32x4 s = {0.f,0.f,0.f,0.f};
    #pragma unroll
    for (int k=0;k<10;k++){
      uint2 cv = *(const uint2*)(base + (size_t)k*150);
      float wk = wa3s[b][k];
      s[0] += bfu((u16)(cv.x & 0xffffu))*wk;
      s[1] += bfu((u16)(cv.x >> 16))*wk;
      s[2] += bfu((u16)(cv.y & 0xffffu))*wk;
      s[3] += bfu((u16)(cv.y >> 16))*wk;
    }
    *(f32x4*)&cats[b][o] = s;
  }
  for (int p=tid;p<TBF*6;p+=NTHR){   // zero cols 300-323
    int b=p/6, c=p%6;
    *(f32x4*)&cats[b][300+4*c] = (f32x4){0.f,0.f,0.f,0.f};
  }
  __syncthreads();
  // ---- fuse1 MFMA: D[b 16][o 112] = cats[16x320] @ fuse1[320x112]; wave=Ntile ----
  if (w < 7){
    f32x4 D = (f32x4){0.f,0.f,0.f,0.f};
    const u16* f1f = (const u16*)((const unsigned*)wsf + OFF_F1F);
    for (int ks=0; ks<10; ks++){
      const int kb = ks*32 + qd*8;
      f32x4 c0 = *(const f32x4*)&cats[lo][kb];
      f32x4 c1 = *(const f32x4*)&cats[lo][kb+4];
      short av[8];
      #pragma unroll
      for (int j=0;j<4;j++){
        av[j]   = (short)f2usr(c0[j]);
        av[4+j] = (short)f2usr(c1[j]);
      }
      s16x8 Ax = (s16x8){av[0],av[1],av[2],av[3],av[4],av[5],av[6],av[7]};
      s16x8 Bf = *(const s16x8*)(f1f + ((size_t)(w*10+ks)*64 + lane)*8);
      D = __builtin_amdgcn_mfma_f32_16x16x32_bf16(Ax, Bf, D, 0,0,0);
    }
    {   // epilogue, all lanes: row = qd*4+r = batch, col = w*16+lo = o
      int o = w*16+lo;
      bool ov = o<100;
      float aa = a[0], swa = wsf[OFF_SWA];
      float bfo = ov? biasf[o] : 0.f;
      float bffo = ov? bff[o]*swa : 0.f;
      float wo = ov? Wout[o] : 0.f;
      #pragma unroll
      for (int r=0;r<4;r++){
        int b = qd*4+r;
        float fu = D[r] + bfo;
        float fd = bffo;
        if (ov){
          #pragma unroll
          for (int f=0;f<17;f++) fd += ff[o*17+f]*dss[b][f];
        }
        float v = (aa*fu + (1.f-aa)*fd) * wo;
        v += __shfl_xor(v,1,64); v += __shfl_xor(v,2,64);
        v += __shfl_xor(v,4,64); v += __shfl_xor(v,8,64);
        if (lo==0) part[w][b] = v;
      }
    }
  }
  __syncthreads();
  if (tid<TBF){
    int b=tid;
    float v = biasout[0];
    #pragma unroll
    for (int ww=0;ww<7;ww++) v += part[ww][b];
    outp[t*512 + b0+b] = v;
  }
}

// ================= weight prep (kprep2 folded into tail thread) =================
__global__ void kprep(const float* __restrict__ Wih, const float* __restrict__ b_ih,
                      const float* __restrict__ b_hh, const float* __restrict__ Wt,
                      const float* __restrict__ bt_ih, const float* __restrict__ bt_hh,
                      const float* __restrict__ wp, const float* __restrict__ F1,
                      const float* __restrict__ b1, const float* __restrict__ fuse1,
                      const float* __restrict__ DisM, float* __restrict__ wsf)
{
  int n = blockIdx.x*256 + threadIdx.x;
  if (n < 92416){   // wp A-frags
    int jp=n&3, lane=(n>>2)&63, rest=n>>8;
    int ks=rest%19, mt=rest/19;
    int m = mt*16 + (lane&15);
    int k = ks*32 + (lane>>4)*8 + 2*jp;
    float v0 = (m<300 && k  <600)? wp[m*600+k  ] : 0.f;
    float v1 = (m<300 && k+1<600)? wp[m*600+k+1] : 0.f;
    ((unsigned*)wsf)[OFF_WBF2+n] = ((unsigned)f2usr(v1)<<16) | f2usr(v0);
    return;
  }
  n -= 92416;
  if (n < 63232){   // F1 B-frags; row 600 = b1
    int jp=n&3, lane=(n>>2)&63, rest=n>>8;
    int ks=rest%19, nt=rest/19;
    int col = nt*16 + (lane&15);
    int k = ks*32 + (lane>>4)*8 + 2*jp;
    float v0=0.f, v1=0.f;
    if (col<200){
      v0 = (k  <600)? F1[k*200+col]     : (k  ==600? b1[col] : 0.f);
      v1 = (k+1<600)? F1[(k+1)*200+col] : (k+1==600? b1[col] : 0.f);
    }
    ((unsigned*)wsf)[OFF_F1S+n] = ((unsigned)f2usr(v1)<<16) | f2usr(v0);
    return;
  }
  n -= 63232;
  if (n < 72960){   // cells B-frags
    int jp=n&3, l32=(n>>2)&31, rest=n>>7;
    int g=rest%3, rest2=rest/3, ht=rest2%19, k=rest2/19;
    int lo=l32&15, q16=l32>>4;
    int h = ht*16 + lo;
    int kk0 = q16*8 + 2*jp;
    float v0=0.f, v1=0.f;
    if (h < 300){
      int G = h + (g==0?0:(g==1?600:900));
      v0 = (kk0  <11)? Wih[(k*1200+G)*11+kk0]
         : (kk0 ==11? b_ih[k*1200+G]+b_hh[k*1200+G] : 0.f);
      int kk1 = kk0+1;
      v1 = (kk1  <11)? Wih[(k*1200+G)*11+kk1]
         : (kk1 ==11? b_ih[k*1200+G]+b_hh[k*1200+G] : 0.f);
    }
    ((unsigned*)wsf)[OFF_WCELL+n] = ((unsigned)f2usr(v1)<<16) | f2usr(v0);
    return;
  }
  n -= 72960;
  if (n < 900){
    int h=n%300, g=n/300;
    int G = h + (g==0?0:(g==1?600:900));
    wsf[OFF_BTP+n] = bt_ih[G]+bt_hh[G]; return;
  }
  n -= 900;
  if (n < 3600){
    int h=n%300; int q=n/300; int g=q%3, e=q/3;
    int G = h + (g==0?0:(g==1?600:900));
    wsf[OFF_WTP+n] = Wt[G*4+e]; return;
  }
  n -= 3600;
  if (n < 17920){   // fuse1 B-frags [nt7][ks10][lane][4]: B[kk][o], kk<300, o<100
    int jp=n&3, lane=(n>>2)&63, rest=n>>8;
    int ks=rest%10, nt=rest/10;
    int col = nt*16 + (lane&15);
    int kk0 = ks*32 + (lane>>4)*8 + 2*jp;
    float v0 = (col<100 && kk0  <300)? fuse1[kk0*100+col]     : 0.f;
    float v1 = (col<100 && kk0+1<300)? fuse1[(kk0+1)*100+col] : 0.f;
    ((unsigned*)wsf)[OFF_F1F+n] = ((unsigned)f2usr(v1)<<16) | f2usr(v0);
    return;
  }
  n -= 17920;
  if (n == 0){   // former kprep2: softmax(DisM) + sum (independent ws region)
    float m = DisM[0];
    for (int k=1;k<10;k++) m = fmaxf(m, DisM[k]);
    float e[10]; float s=0.f;
    for (int k=0;k<10;k++){ e[k]=__expf(DisM[k]-m); s+=e[k]; }
    float inv=1.0f/s; float sw=0.f;
    for (int k=0;k<10;k++){ float v=e[k]*inv; wsf[OFF_WA+k]=v; sw+=v; }
    wsf[OFF_SWA]=sw;
  }
}

extern "C" void kernel_launch(void* const* d_in, const int* in_sizes, int n_in,
                              void* d_out, int out_size, void* d_ws, size_t ws_size,
                              hipStream_t stream)
{
  const float* li     = (const float*)d_in[0];
  const float* labels = (const float*)d_in[1];
  const float* exs    = (const float*)d_in[2];
  const float* DisM   = (const float*)d_in[3];
  const float* AngleM = (const float*)d_in[4];
  const float* Wih    = (const float*)d_in[5];
  const float* b_ih   = (const float*)d_in[6];
  const float* b_hh   = (const float*)d_in[7];
  const float* Wt     = (const float*)d_in[8];
  const float* bt_ih  = (const float*)d_in[9];
  const float* bt_hh  = (const float*)d_in[10];
  const float* wp     = (const float*)d_in[11];
  const float* bp     = (const float*)d_in[12];
  const float* F1     = (const float*)d_in[13];
  const float* b1     = (const float*)d_in[14];
  const float* F2     = (const float*)d_in[15];
  const float* b2     = (const float*)d_in[16];
  const float* ff     = (const float*)d_in[17];
  const float* bff    = (const float*)d_in[18];
  const float* fuse1  = (const float*)d_in[19];
  const float* biasf  = (const float*)d_in[20];
  const float* Wout   = (const float*)d_in[21];
  const float* biasout= (const float*)d_in[22];
  const float* a      = (const float*)d_in[23];
  float* wsf = (float*)d_ws;
  float* outp = (float*)d_out;
  unsigned* con1u = (unsigned*)((char*)d_ws + CON1_BYTE);
  u16* cong = (u16*)((char*)d_ws + CONG_BYTE);

  if (ws_size < WS_NEED_BYTES) return;  // proven available (R12 split ran)

  kprep<<<dim3(981), dim3(256), 0, stream>>>(Wih,b_ih,b_hh,Wt,bt_ih,bt_hh,wp,F1,b1,fuse1,DisM,wsf);
  kern_cells<<<dim3(10,256), dim3(256), 0, stream>>>(li, wsf, cong);
  kern_main_split<<<dim3(NBT,32), NTHR, 0, stream>>>(li, exs, AngleM, bp, F2, b2,
                                                     wsf, con1u, wsf + OFF_SM, cong);
  kern_final<<<dim3(32,32), NTHR, 0, stream>>>(li, labels, ff, bff, biasf,
                                               Wout, biasout, a, wsf, con1u, outp);
}